// Round 7
// baseline (271.467 us; speedup 1.0000x reference)
//
#include <hip/hip_runtime.h>
#include <hip/hip_cooperative_groups.h>
#include <math.h>

namespace cg = cooperative_groups;

#define HW_ 6400
#define C_ 256
#define CP_ 19
#define NBLK 512

typedef __bf16 bf16x8 __attribute__((ext_vector_type(8)));
typedef float  f32x4  __attribute__((ext_vector_type(4)));

// RNE float -> bf16 bits
static __device__ __forceinline__ unsigned short f2bf(float f) {
    union { float f; unsigned int u; } x; x.f = f;
    unsigned int r = x.u + 0x7FFF + ((x.u >> 16) & 1);
    return (unsigned short)(r >> 16);
}

// ---------------------------------------------------------------------------
// Single cooperative kernel, 3 phases separated by grid.sync():
//  A: affinity (aff[49][HW] fp32, S) + wfuse->bf16 + wfeatT*scale->bf16
//     + v[m] = sum_c wfeat[m][c]*shift[c]
//  B: blocks 0..495: agg -> aggT[p][c] bf16 (800 items, strided)
//     blocks 496..511: MFMA wgemm  WTb = (wfuse_b @ wfeatT_b) bf16
//                      + wsum[o] = dot(wfuse[o], v)
//  C: 1600 wave-tiles (16m x 64p): out = x + wsum*S + WTb @ aggT^T
// ---------------------------------------------------------------------------
__global__ __launch_bounds__(256, 2) void mega_kernel(
    const float* __restrict__ cp, const float* __restrict__ sigma,
    const float* __restrict__ wfeat, const float* __restrict__ wfuse,
    const float* __restrict__ g, const float* __restrict__ be,
    const float* __restrict__ mu, const float* __restrict__ var,
    const float* __restrict__ x, float* __restrict__ out,
    float* __restrict__ aff, float* __restrict__ S,
    float* __restrict__ v, float* __restrict__ wsum,
    unsigned short* __restrict__ WTb, unsigned short* __restrict__ wfuse_b,
    unsigned short* __restrict__ wfeatT_b, unsigned short* __restrict__ aggT)
{
    cg::grid_group grid = cg::this_grid();
    const int tid  = threadIdx.x;
    const int lane = tid & 63;
    const int wv   = tid >> 6;
    const int gw   = blockIdx.x * 4 + wv;        // global wave 0..2047
    const int gtid = blockIdx.x * 256 + tid;     // 0..131071
    const int q    = lane >> 4, l15 = lane & 15;

    __shared__ float so[256][9];                 // agg transpose buffer

    // ================= Phase A =================
    // A1: weight converts (one element per thread, both mats exactly covered)
    if (gtid < 65536) {
        wfuse_b[gtid] = f2bf(wfuse[gtid]);
    } else {
        int e = gtid - 65536;
        int m = e >> 8, c = e & 255;
        float scale = g[c] * rsqrtf(var[c] + 1e-5f);
        wfeatT_b[c * C_ + m] = f2bf(wfeat[e] * scale);   // [c][m], scale folded
    }
    // A2: v[m] = sum_c wfeat[m][c] * shift[c]   (waves 0..255)
    if (gw < 256) {
        const int m = gw, c0 = lane * 4;
        float4 wf4 = *(const float4*)&wfeat[m * C_ + c0];
        float sh[4];
#pragma unroll
        for (int e = 0; e < 4; ++e) {
            int c = c0 + e;
            float scale = g[c] * rsqrtf(var[c] + 1e-5f);
            sh[e] = be[c] - mu[c] * scale;
        }
        float part = wf4.x * sh[0] + wf4.y * sh[1] + wf4.z * sh[2] + wf4.w * sh[3];
#pragma unroll
        for (int off = 32; off; off >>= 1) part += __shfl_xor(part, off, 64);
        if (lane == 0) v[m] = part;
    }
    // A3: affinity — one wave per pixel, lane k < 49
    for (int p = gw; p < HW_; p += 2048) {
        const int h = p / 80, w = p - h * 80;
        const int k = (lane < 49) ? lane : 48;
        const int i = k / 7, j = k - i * 7;
        const int hh = h + i - 3, ww = w + j - 3;
        const bool ok = (hh >= 0) & (hh < 80) & (ww >= 0) & (ww < 80);
        const float msk = ok ? 1.0f : 0.0f;          // zero-pad semantics
        int qq = hh * 80 + ww;
        qq = min(max(qq, 0), HW_ - 1);               // always-legal address

        float s = fmaxf(sigma[0], 0.0f);
        float inv_denom = 1.0f / (2.0f * s * s + 1e-8f);
        float d = 0.0f;
#pragma unroll
        for (int c = 0; c < CP_; ++c) {
            float u = cp[c * HW_ + qq];
            float ctr = __shfl(u, 24, 64);           // lane 24 == center px
            float t = u * msk - ctr;
            d += t * t;
        }
        float raw = __expf(-d * inv_denom);
        float e = (lane < 49) ? __expf(raw) : 0.0f;
        float einb = (ok && lane < 49) ? e : 0.0f;
        float sum = e, sumi = einb;
#pragma unroll
        for (int off = 32; off; off >>= 1) {
            sum  += __shfl_xor(sum,  off, 64);
            sumi += __shfl_xor(sumi, off, 64);
        }
        if (lane < 49) aff[k * HW_ + p] = e / sum;
        if (lane == 0) S[p] = sumi / sum;
    }

    grid.sync();

    // ================= Phase B =================
    if (blockIdx.x < 496) {
        // agg: item = pixel-tile x channel-tile; thread = 8 px x 1 ch
        for (int item = blockIdx.x; item < 800; item += 496) {
            const int pgt = item % 25, cht = item / 25;
            const int ch_l = tid >> 5, pg_l = tid & 31;
            const int pg = pgt * 32 + pg_l;
            const int p0 = pg * 8;
            const int h = pg / 10, w0 = (pg - (pg / 10) * 10) * 8;
            const int c = cht * 8 + ch_l;
            const float* xc = x + c * HW_;

            float acc[8] = {0.f, 0.f, 0.f, 0.f, 0.f, 0.f, 0.f, 0.f};
#pragma unroll
            for (int i = 0; i < 7; ++i) {
                int hh = h + i - 3;
                if (hh < 0 || hh >= 80) continue;
                float f[16];
                const int rb = hh * 80;
#pragma unroll
                for (int t = 0; t < 4; ++t) {
                    int lin = rb + w0 - 4 + 4 * t;
                    lin = min(max(lin, rb), rb + 76);
                    *(float4*)&f[4 * t] = *(const float4*)&xc[lin];
                }
#pragma unroll
                for (int e = 0; e < 16; ++e) {
                    int col = w0 - 4 + e;
                    f[e] = (col >= 0 && col < 80) ? f[e] : 0.0f;
                }
#pragma unroll
                for (int j = 0; j < 7; ++j) {
                    const int k = i * 7 + j;
                    float av[8];
                    *(float4*)&av[0] = *(const float4*)&aff[k * HW_ + p0];
                    *(float4*)&av[4] = *(const float4*)&aff[k * HW_ + p0 + 4];
#pragma unroll
                    for (int px = 0; px < 8; ++px)
                        acc[px] += av[px] * f[px + j + 1];
                }
            }
            // LDS transpose -> packed bf16 [p][c] (MFMA B layout)
#pragma unroll
            for (int px = 0; px < 8; ++px) so[pg_l * 8 + px][ch_l] = acc[px];
            __syncthreads();
            unsigned int pk[4];
#pragma unroll
            for (int d = 0; d < 4; ++d) {
                unsigned int lo = f2bf(so[tid][2 * d]);
                unsigned int hi = f2bf(so[tid][2 * d + 1]);
                pk[d] = lo | (hi << 16);
            }
            const int p = pgt * 256 + tid;
            *(uint4*)&aggT[p * C_ + cht * 8] = make_uint4(pk[0], pk[1], pk[2], pk[3]);
            __syncthreads();   // protect `so` for next item
        }
    } else {
        // MFMA wgemm: 64x64 tile per block, wave = 16o x 64c, K=256 (m-dim)
        const int tb = blockIdx.x - 496;             // 0..15
        const int bo = (tb >> 2) * 64, bc = (tb & 3) * 64;
        const int o0 = bo + wv * 16;
        f32x4 acc[4];
#pragma unroll
        for (int nf = 0; nf < 4; ++nf) acc[nf] = (f32x4){0.f, 0.f, 0.f, 0.f};
#pragma unroll
        for (int k0 = 0; k0 < C_; k0 += 32) {
            bf16x8 af = *(const bf16x8*)&wfuse_b[(o0 + l15) * C_ + k0 + q * 8];
            bf16x8 bf[4];
#pragma unroll
            for (int nf = 0; nf < 4; ++nf)
                bf[nf] = *(const bf16x8*)&wfeatT_b[(bc + nf * 16 + l15) * C_ + k0 + q * 8];
#pragma unroll
            for (int nf = 0; nf < 4; ++nf)
                acc[nf] = __builtin_amdgcn_mfma_f32_16x16x32_bf16(af, bf[nf], acc[nf], 0, 0, 0);
        }
#pragma unroll
        for (int nf = 0; nf < 4; ++nf)
#pragma unroll
            for (int r = 0; r < 4; ++r)
                WTb[(o0 + q * 4 + r) * C_ + bc + nf * 16 + l15] = f2bf(acc[nf][r]);
        // wsum: 64 waves x 4 rows = 256 rows; wsum[o] = dot(wfuse[o], v)
        const int gw2 = tb * 4 + wv;
#pragma unroll
        for (int rr = 0; rr < 4; ++rr) {
            const int m = gw2 * 4 + rr, c0 = lane * 4;
            float4 wf4 = *(const float4*)&wfuse[m * C_ + c0];
            float4 v4  = *(const float4*)&v[c0];
            float part = wf4.x * v4.x + wf4.y * v4.y + wf4.z * v4.z + wf4.w * v4.w;
#pragma unroll
            for (int off = 32; off; off >>= 1) part += __shfl_xor(part, off, 64);
            if (lane == 0) wsum[m] = part;
        }
    }

    grid.sync();

    // ================= Phase C =================
    // 1600 wave-tiles of 16m x 64p over 2048 waves
    if (gw < 1600) {
        const int m0 = (gw & 15) * 16;
        const int p0 = (gw >> 4) * 64;
        f32x4 acc[4];
#pragma unroll
        for (int nf = 0; nf < 4; ++nf) acc[nf] = (f32x4){0.f, 0.f, 0.f, 0.f};
#pragma unroll
        for (int k0 = 0; k0 < C_; k0 += 32) {
            bf16x8 af = *(const bf16x8*)&WTb[(m0 + l15) * C_ + k0 + q * 8];
            bf16x8 bf[4];
#pragma unroll
            for (int nf = 0; nf < 4; ++nf)
                bf[nf] = *(const bf16x8*)&aggT[(p0 + nf * 16 + l15) * C_ + k0 + q * 8];
#pragma unroll
            for (int nf = 0; nf < 4; ++nf)
                acc[nf] = __builtin_amdgcn_mfma_f32_16x16x32_bf16(af, bf[nf], acc[nf], 0, 0, 0);
        }
#pragma unroll
        for (int nf = 0; nf < 4; ++nf) {
            const int p = p0 + nf * 16 + l15;
            const float Sp = S[p];
#pragma unroll
            for (int r = 0; r < 4; ++r) {
                const int m = m0 + q * 4 + r;
                out[m * HW_ + p] = x[m * HW_ + p] + wsum[m] * Sp + acc[nf][r];
            }
        }
    }
}

// ---------------------------------------------------------------------------
extern "C" void kernel_launch(void* const* d_in, const int* in_sizes, int n_in,
                              void* d_out, int out_size, void* d_ws, size_t ws_size,
                              hipStream_t stream) {
    const float* x      = (const float*)d_in[0];  // (1,256,80,80)
    const float* cp     = (const float*)d_in[1];  // (1,19,80,80)
    const float* sigma  = (const float*)d_in[2];  // (1,)
    const float* wfeat  = (const float*)d_in[3];  // (256,256)
    const float* wfuse  = (const float*)d_in[4];  // (256,256)
    const float* g      = (const float*)d_in[5];
    const float* be     = (const float*)d_in[6];
    const float* mu     = (const float*)d_in[7];
    const float* var    = (const float*)d_in[8];
    float* out = (float*)d_out;

    char* wsb = (char*)d_ws;
    float* aff  = (float*)wsb;                               // 1.254 MB
    float* S    = aff + 49 * HW_;                            // 25.6 KB
    float* v    = S + HW_;                                   // 1 KB
    float* wsum = v + C_;                                    // 1 KB
    unsigned short* WTb      = (unsigned short*)(wsum + C_); // 128 KB
    unsigned short* wfuse_b  = WTb + 65536;                  // 128 KB
    unsigned short* wfeatT_b = wfuse_b + 65536;              // 128 KB
    unsigned short* aggT     = wfeatT_b + 65536;             // 3.2 MB

    void* args[] = {
        (void*)&cp, (void*)&sigma, (void*)&wfeat, (void*)&wfuse,
        (void*)&g, (void*)&be, (void*)&mu, (void*)&var,
        (void*)&x, (void*)&out,
        (void*)&aff, (void*)&S, (void*)&v, (void*)&wsum,
        (void*)&WTb, (void*)&wfuse_b, (void*)&wfeatT_b, (void*)&aggT,
    };
    hipLaunchCooperativeKernel((void*)mega_kernel, dim3(NBLK), dim3(256),
                               args, 0, stream);
}

// Round 8
// 128.377 us; speedup vs baseline: 2.1146x; 2.1146x over previous
//
#include <hip/hip_runtime.h>
#include <math.h>

#define HW_ 6400
#define C_ 256
#define CP_ 19

typedef __bf16 bf16x8 __attribute__((ext_vector_type(8)));
typedef float  f32x4  __attribute__((ext_vector_type(4)));

// RNE float -> bf16 bits
static __device__ __forceinline__ unsigned short f2bf(float f) {
    union { float f; unsigned int u; } x; x.f = f;
    unsigned int r = x.u + 0x7FFF + ((x.u >> 16) & 1);
    return (unsigned short)(r >> 16);
}
static __device__ __forceinline__ float bf2f(unsigned short u) {
    union { unsigned int ui; float fv; } cv;
    cv.ui = ((unsigned int)u) << 16;
    return cv.fv;
}

// ---------------------------------------------------------------------------
// Dispatch 1: affinity (blocks 0..1599) + wgemm 64x64 tiles (blocks 1600..1615)
//   affinity: one wave per pixel, lane k<49 -> aff[49][HW] fp32, S[p] fp32.
//   wgemm: W = W_fuse @ W_feat, WTb[o][c] = W[o][c]*scale[c] in bf16.
// ---------------------------------------------------------------------------
__global__ __launch_bounds__(256) void prep_kernel(
    const float* __restrict__ cp, const float* __restrict__ sigma,
    const float* __restrict__ wfeat, const float* __restrict__ wfuse,
    const float* __restrict__ g, const float* __restrict__ var,
    float* __restrict__ aff, float* __restrict__ S,
    unsigned short* __restrict__ WTb)
{
    if (blockIdx.x < 1600) {
        // ---------------- affinity ----------------
        const int lane = threadIdx.x & 63;
        const int p = blockIdx.x * 4 + (threadIdx.x >> 6);
        const int h = p / 80, w = p - h * 80;
        const int k = (lane < 49) ? lane : 48;
        const int i = k / 7, j = k - i * 7;
        const int hh = h + i - 3, ww = w + j - 3;
        const bool ok = (hh >= 0) & (hh < 80) & (ww >= 0) & (ww < 80);
        const float msk = ok ? 1.0f : 0.0f;              // zero-pad semantics
        int q = hh * 80 + ww;
        q = min(max(q, 0), HW_ - 1);                     // always-legal address

        float s = fmaxf(sigma[0], 0.0f);
        float inv_denom = 1.0f / (2.0f * s * s + 1e-8f);

        float d = 0.0f;
#pragma unroll
        for (int c = 0; c < CP_; ++c) {
            float u = cp[c * HW_ + q];
            float ctr = __shfl(u, 24, 64);               // lane 24 == center px
            float t = u * msk - ctr;
            d += t * t;
        }
        float raw = __expf(-d * inv_denom);
        float e = (lane < 49) ? __expf(raw) : 0.0f;      // softmax numerator
        float einb = (ok && lane < 49) ? e : 0.0f;
        float sum = e, sumi = einb;
#pragma unroll
        for (int off = 32; off; off >>= 1) {
            sum  += __shfl_xor(sum,  off, 64);
            sumi += __shfl_xor(sumi, off, 64);
        }
        if (lane < 49) aff[k * HW_ + p] = e / sum;
        if (lane == 0) S[p] = sumi / sum;
    } else {
        // ---------------- wgemm tile ----------------
        __shared__ float sA[16][65];   // [k][m]
        __shared__ float sB[16][64];   // [k][n]
        const int tb = blockIdx.x - 1600;
        const int bm = (tb >> 2) * 64, bn = (tb & 3) * 64;
        const int t = threadIdx.x;
        const int arow = t >> 2, akc = (t & 3) * 4;      // A-load coords
        const int bkr = t >> 4, bnc = (t & 15) * 4;      // B-load coords
        const int ty = t >> 4, tx = t & 15;
        float acc[4][4] = {};
        for (int k0 = 0; k0 < C_; k0 += 16) {
            float4 a4 = *(const float4*)&wfuse[(bm + arow) * C_ + k0 + akc];
            sA[akc + 0][arow] = a4.x;
            sA[akc + 1][arow] = a4.y;
            sA[akc + 2][arow] = a4.z;
            sA[akc + 3][arow] = a4.w;
            *(float4*)&sB[bkr][bnc] = *(const float4*)&wfeat[(k0 + bkr) * C_ + bn + bnc];
            __syncthreads();
#pragma unroll
            for (int kk = 0; kk < 16; ++kk) {
                float a[4], b[4];
#pragma unroll
                for (int i = 0; i < 4; ++i) a[i] = sA[kk][ty * 4 + i];
                *(float4*)b = *(const float4*)&sB[kk][tx * 4];
#pragma unroll
                for (int i = 0; i < 4; ++i)
#pragma unroll
                    for (int j = 0; j < 4; ++j) acc[i][j] += a[i] * b[j];
            }
            __syncthreads();
        }
        const int cbase = bn + tx * 4;
        float sc[4];
#pragma unroll
        for (int j = 0; j < 4; ++j)
            sc[j] = g[cbase + j] * rsqrtf(var[cbase + j] + 1e-5f);
#pragma unroll
        for (int i = 0; i < 4; ++i) {
            const int o = bm + ty * 4 + i;
            unsigned int lo = (unsigned int)f2bf(acc[i][0] * sc[0]) |
                              ((unsigned int)f2bf(acc[i][1] * sc[1]) << 16);
            unsigned int hi = (unsigned int)f2bf(acc[i][2] * sc[2]) |
                              ((unsigned int)f2bf(acc[i][3] * sc[3]) << 16);
            *(uint2*)&WTb[o * C_ + cbase] = make_uint2(lo, hi);
        }
    }
}

// ---------------------------------------------------------------------------
// Dispatch 2: agg (blocks 0..399) + wsum (blocks 400..403)
//   agg: aggT[p][c] bf16 = sum_k aff[k][p]*x[c][nbr(p,k)], zero-pad OOB.
//     Thread = 8 px x 2 ch (c and c+8): halves the per-output aff L1 traffic
//     vs 1 ch/thread. Block = 32 px-groups x 8 ch-threads -> 256 px x 16 ch.
//     Grid 400 = 25 px-tiles x 16 ch-tiles; no barriers in compute loop.
//   wsum: wsum[o] = sum_c WTb[o][c]*(be/scale - mu)[c]
// ---------------------------------------------------------------------------
__global__ __launch_bounds__(256) void agg_kernel(
    const float* __restrict__ x, const float* __restrict__ aff,
    const unsigned short* __restrict__ WTb,
    const float* __restrict__ g, const float* __restrict__ be,
    const float* __restrict__ mu, const float* __restrict__ var,
    unsigned short* __restrict__ aggT, float* __restrict__ wsum)
{
    if (blockIdx.x < 400) {
        const int b = blockIdx.x;            // 400 = 25 px-tiles * 16 ch-tiles
        const int pgt = b % 25, cht = b / 25;
        const int ch_l = threadIdx.x >> 5, pg_l = threadIdx.x & 31;
        const int pg = pgt * 32 + pg_l;      // px-group (8 px each)
        const int p0 = pg * 8;
        const int h = pg / 10, w0 = (pg - (pg / 10) * 10) * 8;
        const int c0 = cht * 16 + ch_l;      // channel pair: c0, c0+8
        const float* xc0 = x + c0 * HW_;
        const float* xc1 = x + (c0 + 8) * HW_;

        float acc0[8] = {0.f, 0.f, 0.f, 0.f, 0.f, 0.f, 0.f, 0.f};
        float acc1[8] = {0.f, 0.f, 0.f, 0.f, 0.f, 0.f, 0.f, 0.f};

#pragma unroll
        for (int i = 0; i < 7; ++i) {
            int hh = h + i - 3;
            if (hh < 0 || hh >= 80) continue;
            float f0[16], f1[16];
            const int rb = hh * 80;
#pragma unroll
            for (int t = 0; t < 4; ++t) {
                int lin = rb + w0 - 4 + 4 * t;
                lin = min(max(lin, rb), rb + 76);
                *(float4*)&f0[4 * t] = *(const float4*)&xc0[lin];
                *(float4*)&f1[4 * t] = *(const float4*)&xc1[lin];
            }
#pragma unroll
            for (int e = 0; e < 16; ++e) {
                int col = w0 - 4 + e;
                bool okc = (col >= 0 && col < 80);
                f0[e] = okc ? f0[e] : 0.0f;
                f1[e] = okc ? f1[e] : 0.0f;
            }
#pragma unroll
            for (int j = 0; j < 7; ++j) {
                const int k = i * 7 + j;
                float av[8];
                *(float4*)&av[0] = *(const float4*)&aff[k * HW_ + p0];
                *(float4*)&av[4] = *(const float4*)&aff[k * HW_ + p0 + 4];
#pragma unroll
                for (int px = 0; px < 8; ++px) {
                    acc0[px] += av[px] * f0[px + j + 1];
                    acc1[px] += av[px] * f1[px + j + 1];
                }
            }
        }

        // LDS transpose -> packed bf16 [p][c] stores (MFMA B layout)
        __shared__ float so[256][17];
#pragma unroll
        for (int px = 0; px < 8; ++px) {
            so[pg_l * 8 + px][ch_l]     = acc0[px];
            so[pg_l * 8 + px][ch_l + 8] = acc1[px];
        }
        __syncthreads();
        const int t = threadIdx.x;
        unsigned int pk[8];
#pragma unroll
        for (int d = 0; d < 8; ++d) {
            unsigned int lo = f2bf(so[t][2 * d]);
            unsigned int hi = f2bf(so[t][2 * d + 1]);
            pk[d] = lo | (hi << 16);
        }
        const int p = pgt * 256 + t;
        *(uint4*)&aggT[p * C_ + cht * 16]     = make_uint4(pk[0], pk[1], pk[2], pk[3]);
        *(uint4*)&aggT[p * C_ + cht * 16 + 8] = make_uint4(pk[4], pk[5], pk[6], pk[7]);
    } else {
        // ---------------- wsum ----------------
        __shared__ float srL[C_];
        __shared__ float red[C_];
        const int t = threadIdx.x;
        {
            float scale = g[t] * rsqrtf(var[t] + 1e-5f);
            srL[t] = be[t] / scale - mu[t];
        }
        __syncthreads();
        const int o0 = (blockIdx.x - 400) * 64;
        const int r_l = t >> 2, seg = t & 3;
        const int row = o0 + r_l, c0 = seg * 64;
        float partial = 0.0f;
#pragma unroll
        for (int cc = 0; cc < 64; cc += 8) {
            unsigned short u8[8];
            *(uint4*)u8 = *(const uint4*)&WTb[row * C_ + c0 + cc];
#pragma unroll
            for (int e = 0; e < 8; ++e)
                partial += bf2f(u8[e]) * srL[c0 + cc + e];
        }
        red[t] = partial;
        __syncthreads();
        if (t < 64)
            wsum[o0 + t] = red[t * 4] + red[t * 4 + 1] + red[t * 4 + 2] + red[t * 4 + 3];
    }
}

// ---------------------------------------------------------------------------
// Dispatch 3: MFMA GEMM  out[m][p] = x[m][p] + wsum[m]*S[p] + sum_c W[m][c]*agg[c][p]
//   Wave tile 32m x 64p -> 800 waves (3.1/SIMD). Grid (100,2), 4 waves/block.
//   Fragments are direct 16B global loads (A: WTb rows, B: aggT [p][c] rows).
// ---------------------------------------------------------------------------
__global__ __launch_bounds__(256) void mfma_gemm_kernel(
    const unsigned short* __restrict__ WTb, const unsigned short* __restrict__ aggT,
    const float* __restrict__ wsum, const float* __restrict__ S,
    const float* __restrict__ x, float* __restrict__ out)
{
    const int wave = threadIdx.x >> 6, lane = threadIdx.x & 63;
    const int q = lane >> 4, l15 = lane & 15;
    const int m0 = blockIdx.y * 128 + wave * 32;
    const int px0 = blockIdx.x * 64;

    f32x4 acc[2][4];
#pragma unroll
    for (int mi = 0; mi < 2; ++mi)
#pragma unroll
        for (int ni = 0; ni < 4; ++ni) acc[mi][ni] = (f32x4){0.f, 0.f, 0.f, 0.f};

#pragma unroll
    for (int k0 = 0; k0 < C_; k0 += 32) {
        bf16x8 af[2], bf[4];
#pragma unroll
        for (int mi = 0; mi < 2; ++mi)
            af[mi] = *(const bf16x8*)&WTb[(m0 + mi * 16 + l15) * C_ + k0 + q * 8];
#pragma unroll
        for (int ni = 0; ni < 4; ++ni)
            bf[ni] = *(const bf16x8*)&aggT[(px0 + ni * 16 + l15) * C_ + k0 + q * 8];
#pragma unroll
        for (int mi = 0; mi < 2; ++mi)
#pragma unroll
            for (int ni = 0; ni < 4; ++ni)
                acc[mi][ni] = __builtin_amdgcn_mfma_f32_16x16x32_bf16(
                    af[mi], bf[ni], acc[mi][ni], 0, 0, 0);
    }

#pragma unroll
    for (int mi = 0; mi < 2; ++mi) {
#pragma unroll
        for (int ni = 0; ni < 4; ++ni) {
            int p = px0 + ni * 16 + l15;
            float Sp = S[p];
#pragma unroll
            for (int r = 0; r < 4; ++r) {
                int m = m0 + mi * 16 + q * 4 + r;
                out[m * HW_ + p] = x[m * HW_ + p] + wsum[m] * Sp + acc[mi][ni][r];
            }
        }
    }
}

// ---------------------------------------------------------------------------
extern "C" void kernel_launch(void* const* d_in, const int* in_sizes, int n_in,
                              void* d_out, int out_size, void* d_ws, size_t ws_size,
                              hipStream_t stream) {
    const float* x      = (const float*)d_in[0];  // (1,256,80,80)
    const float* cp     = (const float*)d_in[1];  // (1,19,80,80)
    const float* sigma  = (const float*)d_in[2];  // (1,)
    const float* w_feat = (const float*)d_in[3];  // (256,256)
    const float* w_fuse = (const float*)d_in[4];  // (256,256)
    const float* g      = (const float*)d_in[5];
    const float* be     = (const float*)d_in[6];
    const float* mu     = (const float*)d_in[7];
    const float* var    = (const float*)d_in[8];
    float* out = (float*)d_out;

    char* wsb = (char*)d_ws;
    unsigned short* WTb  = (unsigned short*)wsb;              // 128 KB
    unsigned short* aggT = (unsigned short*)(wsb + 131072);   // 3.2 MB
    float* wsum = (float*)(wsb + 131072 + 3276800);           // 1 KB
    float* S    = wsum + 256;                                 // 25.6 KB
    float* aff  = S + HW_;                                    // 1.25 MB (fp32)
    // total ~4.6 MiB of ws

    prep_kernel<<<1616, 256, 0, stream>>>(cp, sigma, w_feat, w_fuse, g, var,
                                          aff, S, WTb);
    agg_kernel<<<404, 256, 0, stream>>>(x, aff, WTb, g, be, mu, var, aggT, wsum);
    mfma_gemm_kernel<<<dim3(100, 2), 256, 0, stream>>>(WTb, aggT, wsum, S, x, out);
}

// Round 9
// 124.537 us; speedup vs baseline: 2.1798x; 1.0308x over previous
//
#include <hip/hip_runtime.h>
#include <math.h>

#define HW_ 6400
#define C_ 256
#define CP_ 19

typedef __bf16 bf16x8 __attribute__((ext_vector_type(8)));
typedef float  f32x4  __attribute__((ext_vector_type(4)));

// RNE float -> bf16 bits
static __device__ __forceinline__ unsigned short f2bf(float f) {
    union { float f; unsigned int u; } x; x.f = f;
    unsigned int r = x.u + 0x7FFF + ((x.u >> 16) & 1);
    return (unsigned short)(r >> 16);
}
static __device__ __forceinline__ float bf2f(unsigned short u) {
    union { unsigned int ui; float fv; } cv;
    cv.ui = ((unsigned int)u) << 16;
    return cv.fv;
}

union bfpack { unsigned short u[8]; bf16x8 v; };

// ---------------------------------------------------------------------------
// Dispatch 1: affinity (blocks 0..1599) + MFMA wgemm (blocks 1600..1615)
//   affinity: one wave per pixel, lane k<49 -> aff[49][HW] fp32, S[p] fp32.
//   wgemm: WTb[o][c] = (sum_m wfuse[o][m]*wfeat[m][c]) * scale[c], bf16.
//     MFMA 16x16x32 with inline fp32->bf16 converts (A: wfuse rows contiguous;
//     B: wfeat [m][c] natural layout, 8 strided scalar loads per frag).
//     Wave = 16o x 64c, block = 64o x 64c tile, K=256.
// ---------------------------------------------------------------------------
__global__ __launch_bounds__(256) void prep_kernel(
    const float* __restrict__ cp, const float* __restrict__ sigma,
    const float* __restrict__ wfeat, const float* __restrict__ wfuse,
    const float* __restrict__ g, const float* __restrict__ var,
    float* __restrict__ aff, float* __restrict__ S,
    unsigned short* __restrict__ WTb)
{
    if (blockIdx.x < 1600) {
        // ---------------- affinity ----------------
        const int lane = threadIdx.x & 63;
        const int p = blockIdx.x * 4 + (threadIdx.x >> 6);
        const int h = p / 80, w = p - h * 80;
        const int k = (lane < 49) ? lane : 48;
        const int i = k / 7, j = k - i * 7;
        const int hh = h + i - 3, ww = w + j - 3;
        const bool ok = (hh >= 0) & (hh < 80) & (ww >= 0) & (ww < 80);
        const float msk = ok ? 1.0f : 0.0f;              // zero-pad semantics
        int q = hh * 80 + ww;
        q = min(max(q, 0), HW_ - 1);                     // always-legal address

        float s = fmaxf(sigma[0], 0.0f);
        float inv_denom = 1.0f / (2.0f * s * s + 1e-8f);

        float d = 0.0f;
#pragma unroll
        for (int c = 0; c < CP_; ++c) {
            float u = cp[c * HW_ + q];
            float ctr = __shfl(u, 24, 64);               // lane 24 == center px
            float t = u * msk - ctr;
            d += t * t;
        }
        float raw = __expf(-d * inv_denom);
        float e = (lane < 49) ? __expf(raw) : 0.0f;      // softmax numerator
        float einb = (ok && lane < 49) ? e : 0.0f;
        float sum = e, sumi = einb;
#pragma unroll
        for (int off = 32; off; off >>= 1) {
            sum  += __shfl_xor(sum,  off, 64);
            sumi += __shfl_xor(sumi, off, 64);
        }
        if (lane < 49) aff[k * HW_ + p] = e / sum;
        if (lane == 0) S[p] = sumi / sum;
    } else {
        // ---------------- MFMA wgemm ----------------
        const int tb = blockIdx.x - 1600;                // 0..15
        const int wv = threadIdx.x >> 6, lane = threadIdx.x & 63;
        const int q = lane >> 4, l15 = lane & 15;
        const int bo = (tb >> 2) * 64, bc = (tb & 3) * 64;
        const int o0 = bo + wv * 16;

        f32x4 acc[4];
#pragma unroll
        for (int nf = 0; nf < 4; ++nf) acc[nf] = (f32x4){0.f, 0.f, 0.f, 0.f};

        for (int k0 = 0; k0 < C_; k0 += 32) {
            // A frag: wfuse[o0+l15][k0+q*8 .. +8)  (contiguous fp32)
            bfpack ap;
            {
                const float* src = &wfuse[(o0 + l15) * C_ + k0 + q * 8];
                float4 lo = *(const float4*)src;
                float4 hi = *(const float4*)(src + 4);
                ap.u[0] = f2bf(lo.x); ap.u[1] = f2bf(lo.y);
                ap.u[2] = f2bf(lo.z); ap.u[3] = f2bf(lo.w);
                ap.u[4] = f2bf(hi.x); ap.u[5] = f2bf(hi.y);
                ap.u[6] = f2bf(hi.z); ap.u[7] = f2bf(hi.w);
            }
            // B frags: wfeat[k0+q*8+j][bc+nf*16+l15]  (stride-C_ scalar loads)
#pragma unroll
            for (int nf = 0; nf < 4; ++nf) {
                const int cB = bc + nf * 16 + l15;
                bfpack bp;
#pragma unroll
                for (int j = 0; j < 8; ++j)
                    bp.u[j] = f2bf(wfeat[(k0 + q * 8 + j) * C_ + cB]);
                acc[nf] = __builtin_amdgcn_mfma_f32_16x16x32_bf16(
                    ap.v, bp.v, acc[nf], 0, 0, 0);
            }
        }
#pragma unroll
        for (int nf = 0; nf < 4; ++nf) {
            const int c = bc + nf * 16 + l15;
            const float sc = g[c] * rsqrtf(var[c] + 1e-5f);
#pragma unroll
            for (int r = 0; r < 4; ++r)
                WTb[(o0 + q * 4 + r) * C_ + c] = f2bf(acc[nf][r] * sc);
        }
    }
}

// ---------------------------------------------------------------------------
// Dispatch 2: agg (blocks 0..799) + wsum (blocks 800..803)
//   agg: aggT[p][c] bf16 = sum_k aff[k][p]*x[c][nbr(p,k)], zero-pad OOB.
//     Thread = 4 px x 2 ch (c, c+8): keeps halved aff traffic, 2x waves vs R8.
//     Block = 32 px-groups x 8 ch-threads -> 128 px x 16 ch.
//     Grid 800 = 50 px-tiles x 16 ch-tiles (3.1 waves/SIMD), no barriers in
//     the compute loop.
//   wsum: wsum[o] = sum_c WTb[o][c]*(be/scale - mu)[c]
// ---------------------------------------------------------------------------
__global__ __launch_bounds__(256) void agg_kernel(
    const float* __restrict__ x, const float* __restrict__ aff,
    const unsigned short* __restrict__ WTb,
    const float* __restrict__ g, const float* __restrict__ be,
    const float* __restrict__ mu, const float* __restrict__ var,
    unsigned short* __restrict__ aggT, float* __restrict__ wsum)
{
    if (blockIdx.x < 800) {
        const int b = blockIdx.x;            // 800 = 50 px-tiles * 16 ch-tiles
        const int pgt = b % 50, cht = b / 50;
        const int ch_l = threadIdx.x >> 5, pg_l = threadIdx.x & 31;
        const int pg = pgt * 32 + pg_l;      // px-group (4 px each), 0..1599
        const int p0 = pg * 4;
        const int h = pg / 20, w0 = (pg - (pg / 20) * 20) * 4;
        const int c0 = cht * 16 + ch_l;      // channel pair: c0, c0+8
        const float* xc0 = x + c0 * HW_;
        const float* xc1 = x + (c0 + 8) * HW_;

        float acc0[4] = {0.f, 0.f, 0.f, 0.f};
        float acc1[4] = {0.f, 0.f, 0.f, 0.f};

#pragma unroll
        for (int i = 0; i < 7; ++i) {
            int hh = h + i - 3;
            if (hh < 0 || hh >= 80) continue;
            float f0[12], f1[12];
            const int rb = hh * 80;
#pragma unroll
            for (int t = 0; t < 3; ++t) {
                int lin = rb + w0 - 4 + 4 * t;
                lin = min(max(lin, rb), rb + 76);
                *(float4*)&f0[4 * t] = *(const float4*)&xc0[lin];
                *(float4*)&f1[4 * t] = *(const float4*)&xc1[lin];
            }
#pragma unroll
            for (int e = 0; e < 12; ++e) {
                int col = w0 - 4 + e;
                bool okc = (col >= 0 && col < 80);
                f0[e] = okc ? f0[e] : 0.0f;
                f1[e] = okc ? f1[e] : 0.0f;
            }
#pragma unroll
            for (int j = 0; j < 7; ++j) {
                const int k = i * 7 + j;
                float av[4];
                *(float4*)av = *(const float4*)&aff[k * HW_ + p0];
#pragma unroll
                for (int px = 0; px < 4; ++px) {
                    acc0[px] += av[px] * f0[px + j + 1];
                    acc1[px] += av[px] * f1[px + j + 1];
                }
            }
        }

        // LDS transpose -> packed bf16 [p][c] stores (MFMA B layout)
        __shared__ float so[128][17];
#pragma unroll
        for (int px = 0; px < 4; ++px) {
            so[pg_l * 4 + px][ch_l]     = acc0[px];
            so[pg_l * 4 + px][ch_l + 8] = acc1[px];
        }
        __syncthreads();
        const int t = threadIdx.x;
        const int px_i = t >> 1, half = t & 1;   // 128 px x 2 halves
        unsigned int pk[4];
#pragma unroll
        for (int d = 0; d < 4; ++d) {
            unsigned int lo = f2bf(so[px_i][half * 8 + 2 * d]);
            unsigned int hi = f2bf(so[px_i][half * 8 + 2 * d + 1]);
            pk[d] = lo | (hi << 16);
        }
        const int p = pgt * 128 + px_i;
        *(uint4*)&aggT[p * C_ + cht * 16 + half * 8] =
            make_uint4(pk[0], pk[1], pk[2], pk[3]);
    } else {
        // ---------------- wsum ----------------
        __shared__ float srL[C_];
        __shared__ float red[C_];
        const int t = threadIdx.x;
        {
            float scale = g[t] * rsqrtf(var[t] + 1e-5f);
            srL[t] = be[t] / scale - mu[t];
        }
        __syncthreads();
        const int o0 = (blockIdx.x - 800) * 64;
        const int r_l = t >> 2, seg = t & 3;
        const int row = o0 + r_l, c0 = seg * 64;
        float partial = 0.0f;
#pragma unroll
        for (int cc = 0; cc < 64; cc += 8) {
            unsigned short u8[8];
            *(uint4*)u8 = *(const uint4*)&WTb[row * C_ + c0 + cc];
#pragma unroll
            for (int e = 0; e < 8; ++e)
                partial += bf2f(u8[e]) * srL[c0 + cc + e];
        }
        red[t] = partial;
        __syncthreads();
        if (t < 64)
            wsum[o0 + t] = red[t * 4] + red[t * 4 + 1] + red[t * 4 + 2] + red[t * 4 + 3];
    }
}

// ---------------------------------------------------------------------------
// Dispatch 3: MFMA GEMM  out[m][p] = x[m][p] + wsum[m]*S[p] + sum_c W[m][c]*agg[c][p]
//   Wave tile 32m x 64p -> 800 waves (3.1/SIMD). Grid (100,2), 4 waves/block.
//   Fragments are direct 16B global loads (A: WTb rows, B: aggT [p][c] rows).
// ---------------------------------------------------------------------------
__global__ __launch_bounds__(256) void mfma_gemm_kernel(
    const unsigned short* __restrict__ WTb, const unsigned short* __restrict__ aggT,
    const float* __restrict__ wsum, const float* __restrict__ S,
    const float* __restrict__ x, float* __restrict__ out)
{
    const int wave = threadIdx.x >> 6, lane = threadIdx.x & 63;
    const int q = lane >> 4, l15 = lane & 15;
    const int m0 = blockIdx.y * 128 + wave * 32;
    const int px0 = blockIdx.x * 64;

    f32x4 acc[2][4];
#pragma unroll
    for (int mi = 0; mi < 2; ++mi)
#pragma unroll
        for (int ni = 0; ni < 4; ++ni) acc[mi][ni] = (f32x4){0.f, 0.f, 0.f, 0.f};

#pragma unroll
    for (int k0 = 0; k0 < C_; k0 += 32) {
        bf16x8 af[2], bf[4];
#pragma unroll
        for (int mi = 0; mi < 2; ++mi)
            af[mi] = *(const bf16x8*)&WTb[(m0 + mi * 16 + l15) * C_ + k0 + q * 8];
#pragma unroll
        for (int ni = 0; ni < 4; ++ni)
            bf[ni] = *(const bf16x8*)&aggT[(px0 + ni * 16 + l15) * C_ + k0 + q * 8];
#pragma unroll
        for (int mi = 0; mi < 2; ++mi)
#pragma unroll
            for (int ni = 0; ni < 4; ++ni)
                acc[mi][ni] = __builtin_amdgcn_mfma_f32_16x16x32_bf16(
                    af[mi], bf[ni], acc[mi][ni], 0, 0, 0);
    }

#pragma unroll
    for (int mi = 0; mi < 2; ++mi) {
#pragma unroll
        for (int ni = 0; ni < 4; ++ni) {
            int p = px0 + ni * 16 + l15;
            float Sp = S[p];
#pragma unroll
            for (int r = 0; r < 4; ++r) {
                int m = m0 + mi * 16 + q * 4 + r;
                out[m * HW_ + p] = x[m * HW_ + p] + wsum[m] * Sp + acc[mi][ni][r];
            }
        }
    }
}

// ---------------------------------------------------------------------------
extern "C" void kernel_launch(void* const* d_in, const int* in_sizes, int n_in,
                              void* d_out, int out_size, void* d_ws, size_t ws_size,
                              hipStream_t stream) {
    const float* x      = (const float*)d_in[0];  // (1,256,80,80)
    const float* cp     = (const float*)d_in[1];  // (1,19,80,80)
    const float* sigma  = (const float*)d_in[2];  // (1,)
    const float* w_feat = (const float*)d_in[3];  // (256,256)
    const float* w_fuse = (const float*)d_in[4];  // (256,256)
    const float* g      = (const float*)d_in[5];
    const float* be     = (const float*)d_in[6];
    const float* mu     = (const float*)d_in[7];
    const float* var    = (const float*)d_in[8];
    float* out = (float*)d_out;

    char* wsb = (char*)d_ws;
    unsigned short* WTb  = (unsigned short*)wsb;              // 128 KB
    unsigned short* aggT = (unsigned short*)(wsb + 131072);   // 3.2 MB
    float* wsum = (float*)(wsb + 131072 + 3276800);           // 1 KB
    float* S    = wsum + 256;                                 // 25.6 KB
    float* aff  = S + HW_;                                    // 1.25 MB (fp32)
    // total ~4.6 MiB of ws

    prep_kernel<<<1616, 256, 0, stream>>>(cp, sigma, w_feat, w_fuse, g, var,
                                          aff, S, WTb);
    agg_kernel<<<804, 256, 0, stream>>>(x, aff, WTb, g, be, mu, var, aggT, wsum);
    mfma_gemm_kernel<<<dim3(100, 2), 256, 0, stream>>>(WTb, aggT, wsum, S, x, out);
}

// Round 10
// 121.257 us; speedup vs baseline: 2.2388x; 1.0270x over previous
//
#include <hip/hip_runtime.h>
#include <math.h>

#define HW_ 6400
#define C_ 256
#define CP_ 19

typedef __bf16 bf16x8 __attribute__((ext_vector_type(8)));
typedef float  f32x4  __attribute__((ext_vector_type(4)));

// RNE float -> bf16 bits
static __device__ __forceinline__ unsigned short f2bf(float f) {
    union { float f; unsigned int u; } x; x.f = f;
    unsigned int r = x.u + 0x7FFF + ((x.u >> 16) & 1);
    return (unsigned short)(r >> 16);
}
static __device__ __forceinline__ float bf2f(unsigned short u) {
    union { unsigned int ui; float fv; } cv;
    cv.ui = ((unsigned int)u) << 16;
    return cv.fv;
}

union bfpack { unsigned short u[8]; bf16x8 v; };

// ---------------------------------------------------------------------------
// Dispatch 1: affinity (blocks 0..1599) + MFMA wgemm (blocks 1600..1615)
//   affinity: one wave per pixel, lane k<49 -> aff[49][HW] fp32, S[p] fp32.
//   wgemm: WTb[o][c] = (sum_m wfuse[o][m]*wfeat[m][c]) * scale[c], bf16.
// ---------------------------------------------------------------------------
__global__ __launch_bounds__(256) void prep_kernel(
    const float* __restrict__ cp, const float* __restrict__ sigma,
    const float* __restrict__ wfeat, const float* __restrict__ wfuse,
    const float* __restrict__ g, const float* __restrict__ var,
    float* __restrict__ aff, float* __restrict__ S,
    unsigned short* __restrict__ WTb)
{
    if (blockIdx.x < 1600) {
        // ---------------- affinity ----------------
        const int lane = threadIdx.x & 63;
        const int p = blockIdx.x * 4 + (threadIdx.x >> 6);
        const int h = p / 80, w = p - h * 80;
        const int k = (lane < 49) ? lane : 48;
        const int i = k / 7, j = k - i * 7;
        const int hh = h + i - 3, ww = w + j - 3;
        const bool ok = (hh >= 0) & (hh < 80) & (ww >= 0) & (ww < 80);
        const float msk = ok ? 1.0f : 0.0f;              // zero-pad semantics
        int q = hh * 80 + ww;
        q = min(max(q, 0), HW_ - 1);                     // always-legal address

        float s = fmaxf(sigma[0], 0.0f);
        float inv_denom = 1.0f / (2.0f * s * s + 1e-8f);

        float d = 0.0f;
#pragma unroll
        for (int c = 0; c < CP_; ++c) {
            float u = cp[c * HW_ + q];
            float ctr = __shfl(u, 24, 64);               // lane 24 == center px
            float t = u * msk - ctr;
            d += t * t;
        }
        float raw = __expf(-d * inv_denom);
        float e = (lane < 49) ? __expf(raw) : 0.0f;      // softmax numerator
        float einb = (ok && lane < 49) ? e : 0.0f;
        float sum = e, sumi = einb;
#pragma unroll
        for (int off = 32; off; off >>= 1) {
            sum  += __shfl_xor(sum,  off, 64);
            sumi += __shfl_xor(sumi, off, 64);
        }
        if (lane < 49) aff[k * HW_ + p] = e / sum;
        if (lane == 0) S[p] = sumi / sum;
    } else {
        // ---------------- MFMA wgemm ----------------
        const int tb = blockIdx.x - 1600;                // 0..15
        const int wv = threadIdx.x >> 6, lane = threadIdx.x & 63;
        const int q = lane >> 4, l15 = lane & 15;
        const int bo = (tb >> 2) * 64, bc = (tb & 3) * 64;
        const int o0 = bo + wv * 16;

        f32x4 acc[4];
#pragma unroll
        for (int nf = 0; nf < 4; ++nf) acc[nf] = (f32x4){0.f, 0.f, 0.f, 0.f};

        for (int k0 = 0; k0 < C_; k0 += 32) {
            bfpack ap;
            {
                const float* src = &wfuse[(o0 + l15) * C_ + k0 + q * 8];
                float4 lo = *(const float4*)src;
                float4 hi = *(const float4*)(src + 4);
                ap.u[0] = f2bf(lo.x); ap.u[1] = f2bf(lo.y);
                ap.u[2] = f2bf(lo.z); ap.u[3] = f2bf(lo.w);
                ap.u[4] = f2bf(hi.x); ap.u[5] = f2bf(hi.y);
                ap.u[6] = f2bf(hi.z); ap.u[7] = f2bf(hi.w);
            }
#pragma unroll
            for (int nf = 0; nf < 4; ++nf) {
                const int cB = bc + nf * 16 + l15;
                bfpack bp;
#pragma unroll
                for (int j = 0; j < 8; ++j)
                    bp.u[j] = f2bf(wfeat[(k0 + q * 8 + j) * C_ + cB]);
                acc[nf] = __builtin_amdgcn_mfma_f32_16x16x32_bf16(
                    ap.v, bp.v, acc[nf], 0, 0, 0);
            }
        }
#pragma unroll
        for (int nf = 0; nf < 4; ++nf) {
            const int c = bc + nf * 16 + l15;
            const float sc = g[c] * rsqrtf(var[c] + 1e-5f);
#pragma unroll
            for (int r = 0; r < 4; ++r)
                WTb[(o0 + q * 4 + r) * C_ + c] = f2bf(acc[nf][r] * sc);
        }
    }
}

// ---------------------------------------------------------------------------
// Dispatch 2: agg (blocks 0..799) + wsum (blocks 800..803)
//   agg: aggT[p][c] bf16 = sum_k aff[k][p]*x[c][nbr(p,k)], zero-pad OOB.
//     Thread = 4 px x 2 ch (c, c+8). Block = 128 px x 16 ch.
//     NEW: block's aff slice (49 k x 128 px = 25 KB) staged in LDS once —
//     cuts the 8x-duplicated global aff loads to ~6 float4/thread; compute
//     reads aff via contiguous ds_read_b128 (broadcast across ch-threads).
//     Grid 800 = 50 px-tiles x 16 ch-tiles (3.1 waves/SIMD).
//   wsum: wsum[o] = sum_c WTb[o][c]*(be/scale - mu)[c]
// ---------------------------------------------------------------------------
__global__ __launch_bounds__(256) void agg_kernel(
    const float* __restrict__ x, const float* __restrict__ aff,
    const unsigned short* __restrict__ WTb,
    const float* __restrict__ g, const float* __restrict__ be,
    const float* __restrict__ mu, const float* __restrict__ var,
    unsigned short* __restrict__ aggT, float* __restrict__ wsum)
{
    if (blockIdx.x < 800) {
        const int b = blockIdx.x;            // 800 = 50 px-tiles * 16 ch-tiles
        const int pgt = b % 50, cht = b / 50;
        const int ch_l = threadIdx.x >> 5, pg_l = threadIdx.x & 31;
        const int P0 = pgt * 128;            // block px base
        const int pg = pgt * 32 + pg_l;      // px-group (4 px each)
        const int h = pg / 20, w0 = (pg - (pg / 20) * 20) * 4;
        const int c0 = cht * 16 + ch_l;      // channel pair: c0, c0+8
        const float* xc0 = x + c0 * HW_;
        const float* xc1 = x + (c0 + 8) * HW_;

        // ---- stage aff[49][P0..P0+128) into LDS ----
        __shared__ __align__(16) float safL[49 * 128];   // 25 KB
        for (int idx = threadIdx.x; idx < 49 * 32; idx += 256) {
            const int k = idx >> 5, off4 = (idx & 31) * 4;
            *(float4*)&safL[k * 128 + off4] =
                *(const float4*)&aff[k * HW_ + P0 + off4];
        }
        __syncthreads();

        float acc0[4] = {0.f, 0.f, 0.f, 0.f};
        float acc1[4] = {0.f, 0.f, 0.f, 0.f};

#pragma unroll
        for (int i = 0; i < 7; ++i) {
            int hh = h + i - 3;
            if (hh < 0 || hh >= 80) continue;
            float f0[12], f1[12];
            const int rb = hh * 80;
#pragma unroll
            for (int t = 0; t < 3; ++t) {
                int lin = rb + w0 - 4 + 4 * t;
                lin = min(max(lin, rb), rb + 76);
                *(float4*)&f0[4 * t] = *(const float4*)&xc0[lin];
                *(float4*)&f1[4 * t] = *(const float4*)&xc1[lin];
            }
#pragma unroll
            for (int e = 0; e < 12; ++e) {
                int col = w0 - 4 + e;
                bool okc = (col >= 0 && col < 80);
                f0[e] = okc ? f0[e] : 0.0f;
                f1[e] = okc ? f1[e] : 0.0f;
            }
#pragma unroll
            for (int j = 0; j < 7; ++j) {
                const int k = i * 7 + j;
                float av[4];
                *(float4*)av = *(const float4*)&safL[k * 128 + pg_l * 4];
#pragma unroll
                for (int px = 0; px < 4; ++px) {
                    acc0[px] += av[px] * f0[px + j + 1];
                    acc1[px] += av[px] * f1[px + j + 1];
                }
            }
        }

        // LDS transpose -> packed bf16 [p][c] stores (MFMA B layout)
        __shared__ float so[128][17];
#pragma unroll
        for (int px = 0; px < 4; ++px) {
            so[pg_l * 4 + px][ch_l]     = acc0[px];
            so[pg_l * 4 + px][ch_l + 8] = acc1[px];
        }
        __syncthreads();
        const int t = threadIdx.x;
        const int px_i = t >> 1, half = t & 1;   // 128 px x 2 halves
        unsigned int pk[4];
#pragma unroll
        for (int d = 0; d < 4; ++d) {
            unsigned int lo = f2bf(so[px_i][half * 8 + 2 * d]);
            unsigned int hi = f2bf(so[px_i][half * 8 + 2 * d + 1]);
            pk[d] = lo | (hi << 16);
        }
        const int p = pgt * 128 + px_i;
        *(uint4*)&aggT[p * C_ + cht * 16 + half * 8] =
            make_uint4(pk[0], pk[1], pk[2], pk[3]);
    } else {
        // ---------------- wsum ----------------
        __shared__ float srL[C_];
        __shared__ float red[C_];
        const int t = threadIdx.x;
        {
            float scale = g[t] * rsqrtf(var[t] + 1e-5f);
            srL[t] = be[t] / scale - mu[t];
        }
        __syncthreads();
        const int o0 = (blockIdx.x - 800) * 64;
        const int r_l = t >> 2, seg = t & 3;
        const int row = o0 + r_l, c0 = seg * 64;
        float partial = 0.0f;
#pragma unroll
        for (int cc = 0; cc < 64; cc += 8) {
            unsigned short u8[8];
            *(uint4*)u8 = *(const uint4*)&WTb[row * C_ + c0 + cc];
#pragma unroll
            for (int e = 0; e < 8; ++e)
                partial += bf2f(u8[e]) * srL[c0 + cc + e];
        }
        red[t] = partial;
        __syncthreads();
        if (t < 64)
            wsum[o0 + t] = red[t * 4] + red[t * 4 + 1] + red[t * 4 + 2] + red[t * 4 + 3];
    }
}

// ---------------------------------------------------------------------------
// Dispatch 3: MFMA GEMM  out[m][p] = x[m][p] + wsum[m]*S[p] + sum_c W[m][c]*agg[c][p]
//   Wave tile 32m x 64p -> 800 waves (3.1/SIMD). Grid (100,2), 4 waves/block.
// ---------------------------------------------------------------------------
__global__ __launch_bounds__(256) void mfma_gemm_kernel(
    const unsigned short* __restrict__ WTb, const unsigned short* __restrict__ aggT,
    const float* __restrict__ wsum, const float* __restrict__ S,
    const float* __restrict__ x, float* __restrict__ out)
{
    const int wave = threadIdx.x >> 6, lane = threadIdx.x & 63;
    const int q = lane >> 4, l15 = lane & 15;
    const int m0 = blockIdx.y * 128 + wave * 32;
    const int px0 = blockIdx.x * 64;

    f32x4 acc[2][4];
#pragma unroll
    for (int mi = 0; mi < 2; ++mi)
#pragma unroll
        for (int ni = 0; ni < 4; ++ni) acc[mi][ni] = (f32x4){0.f, 0.f, 0.f, 0.f};

#pragma unroll
    for (int k0 = 0; k0 < C_; k0 += 32) {
        bf16x8 af[2], bf[4];
#pragma unroll
        for (int mi = 0; mi < 2; ++mi)
            af[mi] = *(const bf16x8*)&WTb[(m0 + mi * 16 + l15) * C_ + k0 + q * 8];
#pragma unroll
        for (int ni = 0; ni < 4; ++ni)
            bf[ni] = *(const bf16x8*)&aggT[(px0 + ni * 16 + l15) * C_ + k0 + q * 8];
#pragma unroll
        for (int mi = 0; mi < 2; ++mi)
#pragma unroll
            for (int ni = 0; ni < 4; ++ni)
                acc[mi][ni] = __builtin_amdgcn_mfma_f32_16x16x32_bf16(
                    af[mi], bf[ni], acc[mi][ni], 0, 0, 0);
    }

#pragma unroll
    for (int mi = 0; mi < 2; ++mi) {
#pragma unroll
        for (int ni = 0; ni < 4; ++ni) {
            int p = px0 + ni * 16 + l15;
            float Sp = S[p];
#pragma unroll
            for (int r = 0; r < 4; ++r) {
                int m = m0 + mi * 16 + q * 4 + r;
                out[m * HW_ + p] = x[m * HW_ + p] + wsum[m] * Sp + acc[mi][ni][r];
            }
        }
    }
}

// ---------------------------------------------------------------------------
extern "C" void kernel_launch(void* const* d_in, const int* in_sizes, int n_in,
                              void* d_out, int out_size, void* d_ws, size_t ws_size,
                              hipStream_t stream) {
    const float* x      = (const float*)d_in[0];  // (1,256,80,80)
    const float* cp     = (const float*)d_in[1];  // (1,19,80,80)
    const float* sigma  = (const float*)d_in[2];  // (1,)
    const float* w_feat = (const float*)d_in[3];  // (256,256)
    const float* w_fuse = (const float*)d_in[4];  // (256,256)
    const float* g      = (const float*)d_in[5];
    const float* be     = (const float*)d_in[6];
    const float* mu     = (const float*)d_in[7];
    const float* var    = (const float*)d_in[8];
    float* out = (float*)d_out;

    char* wsb = (char*)d_ws;
    unsigned short* WTb  = (unsigned short*)wsb;              // 128 KB
    unsigned short* aggT = (unsigned short*)(wsb + 131072);   // 3.2 MB
    float* wsum = (float*)(wsb + 131072 + 3276800);           // 1 KB
    float* S    = wsum + 256;                                 // 25.6 KB
    float* aff  = S + HW_;                                    // 1.25 MB (fp32)
    // total ~4.6 MiB of ws

    prep_kernel<<<1616, 256, 0, stream>>>(cp, sigma, w_feat, w_fuse, g, var,
                                          aff, S, WTb);
    agg_kernel<<<804, 256, 0, stream>>>(x, aff, WTb, g, be, mu, var, aggT, wsum);
    mfma_gemm_kernel<<<dim3(100, 2), 256, 0, stream>>>(WTb, aggT, wsum, S, x, out);
}